// Round 2
// baseline (4717.465 us; speedup 1.0000x reference)
//
#include <hip/hip_runtime.h>
#include <math.h>

constexpr int Bn = 8;
constexpr int Np = 2048;
constexpr int Kn = 32;
constexpr float NEGS = 0.2f;

__device__ __forceinline__ float lrelu(float v) { return v > 0.f ? v : NEGS * v; }

// x [B,3,N] -> pts point-major [B*N, 4] (pad lane = 0)
__global__ __launch_bounds__(256) void k_transpose(const float* __restrict__ x, float* __restrict__ pts) {
    int i = blockIdx.x * 256 + threadIdx.x;
    int b = i / Np, n = i % Np;
    float p0 = x[((size_t)b * 3 + 0) * Np + n];
    float p1 = x[((size_t)b * 3 + 1) * Np + n];
    float p2 = x[((size_t)b * 3 + 2) * Np + n];
    float4 v = make_float4(p0, p1, p2, 0.f);
    *(float4*)&pts[(size_t)i * 4] = v;
}

// xx[i] = sum_c pm[i*ld+c]^2 ; one wave per point, 4 points per block
__global__ __launch_bounds__(256) void k_xx(const float* __restrict__ pm, float* __restrict__ xxg, int C, int ld) {
    int wid = threadIdx.x >> 6, lane = threadIdx.x & 63;
    int pt = blockIdx.x * 4 + wid;
    const float* row = pm + (size_t)pt * ld;
    float acc = 0.f;
    for (int c = lane; c < C; c += 64) { float v = row[c]; acc = fmaf(v, v, acc); }
    #pragma unroll
    for (int off = 32; off; off >>= 1) acc += __shfl_down(acc, off, 64);
    if (lane == 0) xxg[pt] = acc;
}

// kNN top-32 (largest of d = 2*inner - xx_n - xx_m). 4 rows per block.
template<int C>
__global__ __launch_bounds__(256) void k_knn(const float* __restrict__ Xcm, const float* __restrict__ Xpm, int ld,
                                             const float* __restrict__ xxg, int* __restrict__ idxo) {
    __shared__ float pcs[4][C];
    __shared__ float dl[4 * Np];
    int blk = blockIdx.x;
    int b = blk / (Np / 4);
    int n0 = (blk % (Np / 4)) * 4;
    int t = threadIdx.x;
    for (int e = t; e < 4 * C; e += 256) {
        int r = e / C, c = e % C;
        pcs[r][c] = Xpm[((size_t)b * Np + n0 + r) * ld + c];
    }
    __syncthreads();
    float dot[4][8] = {};
    for (int c = 0; c < C; ++c) {
        float p0 = pcs[0][c], p1 = pcs[1][c], p2 = pcs[2][c], p3 = pcs[3][c];
        const float* xrow = Xcm + ((size_t)b * C + c) * Np;
        #pragma unroll
        for (int j = 0; j < 8; ++j) {
            float xm = xrow[t + 256 * j];
            dot[0][j] = fmaf(p0, xm, dot[0][j]);
            dot[1][j] = fmaf(p1, xm, dot[1][j]);
            dot[2][j] = fmaf(p2, xm, dot[2][j]);
            dot[3][j] = fmaf(p3, xm, dot[3][j]);
        }
    }
    float xc0 = xxg[b * Np + n0 + 0], xc1 = xxg[b * Np + n0 + 1];
    float xc2 = xxg[b * Np + n0 + 2], xc3 = xxg[b * Np + n0 + 3];
    #pragma unroll
    for (int j = 0; j < 8; ++j) {
        int m = t + 256 * j;
        float xm = xxg[b * Np + m];
        dl[0 * Np + m] = 2.f * dot[0][j] - xc0 - xm;
        dl[1 * Np + m] = 2.f * dot[1][j] - xc1 - xm;
        dl[2 * Np + m] = 2.f * dot[2][j] - xc2 - xm;
        dl[3 * Np + m] = 2.f * dot[3][j] - xc3 - xm;
    }
    __syncthreads();
    int w = t >> 6, lane = t & 63;
    float v[32];
    #pragma unroll
    for (int j = 0; j < 32; ++j) v[j] = dl[w * Np + lane + 64 * j];
    size_t ob = ((size_t)b * Np + n0 + w) * Kn;
    for (int it = 0; it < Kn; ++it) {
        float bv = v[0]; int bj = 0;
        #pragma unroll
        for (int j = 1; j < 32; ++j) if (v[j] > bv) { bv = v[j]; bj = j; }
        int bm = lane + 64 * bj;
        #pragma unroll
        for (int off = 32; off; off >>= 1) {
            float ov = __shfl_down(bv, off, 64);
            int om = __shfl_down(bm, off, 64);
            if (ov > bv || (ov == bv && om < bm)) { bv = ov; bm = om; }
        }
        bm = __shfl(bm, 0, 64);
        if ((bm & 63) == lane) v[bm >> 6] = -INFINITY;
        if (lane == 0) idxo[ob + it] = bm;
    }
}

// Fused EdgeConv: gather nbr -> LDS (padded stride), h = nbr.Wn + ctr.(Wc-Wn), BN+LeakyReLU, max over k.
// 256 threads = OG (outputs) x NKG (k-groups); OPT outputs/thread, KPT neighbors/thread, PTS points/block.
// OPT chosen so each ds_read_b128 feeds >=16 FMA (LDS-BW balance). k-reduction: shfl_xor + tiny LDS.
template<int C, int CPAD, int O, int OPT, int KPT, int PTS>
__global__ __launch_bounds__(256) void k_edgeconv(
    const float* __restrict__ Xpm, const int* __restrict__ idxg,
    const float* __restrict__ W, const float* __restrict__ sg, const float* __restrict__ bg,
    float* __restrict__ Ypm, float* __restrict__ Ycm, int wcm)
{
    constexpr int OG = O / OPT;
    constexpr int NKG = 256 / OG;
    constexpr int CL = CPAD + 4;          // padded LDS row stride: kg-groups land 8 banks apart
    static_assert(NKG * KPT == Kn, "k mapping");
    __shared__ float nbr[PTS][Kn][CL];
    __shared__ float ctr[PTS][CPAD];
    __shared__ float red[PTS][OPT][4][OG];
    int blk = blockIdx.x;
    int b = blk / (Np / PTS);
    int n0 = (blk % (Np / PTS)) * PTS;
    int t = threadIdx.x;
    int lane = t & 63, wid = t >> 6;
    const int* ip = idxg + ((size_t)b * Np + n0) * Kn;
    const float4* Xp4 = (const float4*)Xpm;
    constexpr int C4 = CPAD / 4;
    for (int e = t; e < PTS * C4; e += 256) {
        int pt = e / C4, c4 = e % C4;
        *(float4*)&ctr[pt][4 * c4] = Xp4[((size_t)b * Np + n0 + pt) * C4 + c4];
    }
    for (int e = t; e < PTS * Kn * C4; e += 256) {
        int pt = e / (Kn * C4);
        int r = e % (Kn * C4);
        int k = r / C4, c4 = r % C4;
        int nb = ip[pt * Kn + k];
        *(float4*)&nbr[pt][k][4 * c4] = Xp4[((size_t)b * Np + nb) * C4 + c4];
    }
    __syncthreads();
    int og = t % OG, kg = t / OG;
    float acc[PTS][OPT][KPT] = {};
    float ctt[PTS][OPT] = {};
    for (int c0 = 0; c0 < CPAD; c0 += 4) {
        float wn[OPT][4], wd[OPT][4];
        #pragma unroll
        for (int p = 0; p < OPT; ++p) {
            int o = og + p * OG;
            if constexpr (C % 4 == 0) {
                float4 a = *(const float4*)(W + (size_t)o * (2 * C) + c0);
                float4 q = *(const float4*)(W + (size_t)o * (2 * C) + C + c0);
                wn[p][0] = a.x; wn[p][1] = a.y; wn[p][2] = a.z; wn[p][3] = a.w;
                wd[p][0] = q.x - a.x; wd[p][1] = q.y - a.y; wd[p][2] = q.z - a.z; wd[p][3] = q.w - a.w;
            } else {
                #pragma unroll
                for (int cc = 0; cc < 4; ++cc) {
                    int c = c0 + cc;
                    float a = (c < C) ? W[(size_t)o * (2 * C) + c] : 0.f;
                    float q = (c < C) ? W[(size_t)o * (2 * C) + C + c] : 0.f;
                    wn[p][cc] = a; wd[p][cc] = q - a;
                }
            }
        }
        #pragma unroll
        for (int pt = 0; pt < PTS; ++pt) {
            float4 cv = *(const float4*)&ctr[pt][c0];
            #pragma unroll
            for (int p = 0; p < OPT; ++p) {
                ctt[pt][p] = fmaf(wd[p][0], cv.x, ctt[pt][p]);
                ctt[pt][p] = fmaf(wd[p][1], cv.y, ctt[pt][p]);
                ctt[pt][p] = fmaf(wd[p][2], cv.z, ctt[pt][p]);
                ctt[pt][p] = fmaf(wd[p][3], cv.w, ctt[pt][p]);
            }
        }
        #pragma unroll
        for (int pt = 0; pt < PTS; ++pt) {
            #pragma unroll
            for (int k = 0; k < KPT; ++k) {
                float4 nv = *(const float4*)&nbr[pt][kg * KPT + k][c0];
                #pragma unroll
                for (int p = 0; p < OPT; ++p) {
                    acc[pt][p][k] = fmaf(wn[p][0], nv.x, acc[pt][p][k]);
                    acc[pt][p][k] = fmaf(wn[p][1], nv.y, acc[pt][p][k]);
                    acc[pt][p][k] = fmaf(wn[p][2], nv.z, acc[pt][p][k]);
                    acc[pt][p][k] = fmaf(wn[p][3], nv.w, acc[pt][p][k]);
                }
            }
        }
    }
    #pragma unroll
    for (int pt = 0; pt < PTS; ++pt) {
        #pragma unroll
        for (int p = 0; p < OPT; ++p) {
            int o = og + p * OG;
            float sv = sg[o], bv = bg[o];
            float m = -INFINITY;
            #pragma unroll
            for (int k = 0; k < KPT; ++k) {
                float hv = fmaf(acc[pt][p][k] + ctt[pt][p], sv, bv);
                m = fmaxf(m, lrelu(hv));
            }
            #pragma unroll
            for (int s = OG; s < 64; s <<= 1) m = fmaxf(m, __shfl_xor(m, s, 64));
            if (lane < OG) red[pt][p][wid][lane] = m;
        }
    }
    __syncthreads();
    if (t < OG) {
        #pragma unroll
        for (int pt = 0; pt < PTS; ++pt) {
            #pragma unroll
            for (int p = 0; p < OPT; ++p) {
                float m = fmaxf(fmaxf(red[pt][p][0][t], red[pt][p][1][t]),
                                fmaxf(red[pt][p][2][t], red[pt][p][3][t]));
                int o = t + p * OG;
                Ypm[((size_t)b * Np + n0 + pt) * O + o] = m;
                if (wcm) Ycm[((size_t)b * O + o) * Np + n0 + pt] = m;
            }
        }
    }
}

// W5 transpose [1024][512] -> [512][1024] (32x32 LDS tiles)
__global__ __launch_bounds__(256) void k_w5t(const float* __restrict__ W5, float* __restrict__ W5t) {
    __shared__ float tile[32][33];
    int o0 = (blockIdx.x & 31) * 32;
    int c0 = (blockIdx.x >> 5) * 32;
    int lr = threadIdx.x >> 5, lc = threadIdx.x & 31;
    #pragma unroll
    for (int j = 0; j < 4; ++j) {
        int r = lr + 8 * j;
        tile[r][lc] = W5[(size_t)(o0 + r) * 512 + c0 + lc];
    }
    __syncthreads();
    #pragma unroll
    for (int j = 0; j < 4; ++j) {
        int r = lr + 8 * j;
        W5t[(size_t)(c0 + r) * 1024 + o0 + lc] = tile[lc][r];
    }
}

// W5 (channel-major W5t) + BN + LeakyReLU + per-block max/sum over 32 points -> partials (no atomics).
__global__ __launch_bounds__(256) void k_w5pool(
    const float* __restrict__ x1, const float* __restrict__ x2,
    const float* __restrict__ x3, const float* __restrict__ x4,
    const float* __restrict__ W5t, const float* __restrict__ s5, const float* __restrict__ b5,
    float* __restrict__ pmax, float* __restrict__ psum)
{
    constexpr int PP = 16;   // points per pass
    __shared__ float cat[PP][512];
    int blk = blockIdx.x;
    int b = blk >> 6;            // Np/32 = 64 chunks
    int chunk = blk & 63;
    int n0 = chunk * 32;
    int t = threadIdx.x;
    float mx[4] = {-INFINITY, -INFINITY, -INFINITY, -INFINITY};
    float sm[4] = {};
    for (int pass = 0; pass < 2; ++pass) {
        __syncthreads();
        for (int e = t; e < PP * 128; e += 256) {
            int pt = e >> 7, c4 = e & 127;
            size_t pi = (size_t)b * Np + n0 + pass * PP + pt;
            float4 v;
            if (c4 < 16)      v = ((const float4*)x1)[pi * 16 + c4];
            else if (c4 < 32) v = ((const float4*)x2)[pi * 16 + (c4 - 16)];
            else if (c4 < 64) v = ((const float4*)x3)[pi * 32 + (c4 - 32)];
            else              v = ((const float4*)x4)[pi * 64 + (c4 - 64)];
            *(float4*)&cat[pt][4 * c4] = v;
        }
        __syncthreads();
        float acc[4][PP] = {};
        for (int c0 = 0; c0 < 512; c0 += 4) {
            float wv[4][4];
            #pragma unroll
            for (int j = 0; j < 4; ++j) {
                const float* row = W5t + (size_t)(c0 + j) * 1024 + t;
                #pragma unroll
                for (int r = 0; r < 4; ++r) wv[j][r] = row[256 * r];
            }
            #pragma unroll
            for (int pt = 0; pt < PP; ++pt) {
                float4 cv = *(const float4*)&cat[pt][c0];
                #pragma unroll
                for (int r = 0; r < 4; ++r) {
                    acc[r][pt] = fmaf(wv[0][r], cv.x, acc[r][pt]);
                    acc[r][pt] = fmaf(wv[1][r], cv.y, acc[r][pt]);
                    acc[r][pt] = fmaf(wv[2][r], cv.z, acc[r][pt]);
                    acc[r][pt] = fmaf(wv[3][r], cv.w, acc[r][pt]);
                }
            }
        }
        #pragma unroll
        for (int r = 0; r < 4; ++r) {
            int o = t + 256 * r;
            float sv = s5[o], bv = b5[o];
            #pragma unroll
            for (int pt = 0; pt < PP; ++pt) {
                float v = lrelu(fmaf(acc[r][pt], sv, bv));
                mx[r] = fmaxf(mx[r], v);
                sm[r] += v;
            }
        }
    }
    #pragma unroll
    for (int r = 0; r < 4; ++r) {
        int o = t + 256 * r;
        pmax[((size_t)(b * 64 + chunk)) * 1024 + o] = mx[r];
        psum[((size_t)(b * 64 + chunk)) * 1024 + o] = sm[r];
    }
}

// reduce 64 chunks -> g0[b,0:1024]=max, g0[b,1024:2048]=mean
__global__ __launch_bounds__(256) void k_poolred(const float* __restrict__ pmax, const float* __restrict__ psum,
                                                 float* __restrict__ g0) {
    int i = blockIdx.x * 256 + threadIdx.x;   // B*1024
    int b = i >> 10, o = i & 1023;
    float mx = -INFINITY, sm = 0.f;
    for (int ch = 0; ch < 64; ++ch) {
        size_t idx = ((size_t)(b * 64 + ch)) * 1024 + o;
        mx = fmaxf(mx, pmax[idx]);
        sm += psum[idx];
    }
    g0[(size_t)b * 2048 + o] = mx;
    g0[(size_t)b * 2048 + 1024 + o] = sm * (1.f / Np);
}

// Generic FC: out[b,o] = act((dot(In[b,:C], W[o,:]) + bias) * s + bnb). One wave per output.
__global__ __launch_bounds__(256) void k_fc(const float* __restrict__ In, int ldIn, int C,
                                            const float* __restrict__ Wm,
                                            const float* __restrict__ bias,
                                            const float* __restrict__ sc, const float* __restrict__ bnb,
                                            int leaky, float* __restrict__ Out, int ldOut, int O) {
    int wid = threadIdx.x >> 6, lane = threadIdx.x & 63;
    int o = blockIdx.x * 4 + wid;
    int b = blockIdx.y;
    if (o >= O) return;
    const float* in = In + (size_t)b * ldIn;
    const float* wr = Wm + (size_t)o * C;
    float acc = 0.f;
    for (int c = lane; c < C; c += 64) acc = fmaf(in[c], wr[c], acc);
    #pragma unroll
    for (int off = 32; off; off >>= 1) acc += __shfl_down(acc, off, 64);
    if (lane == 0) {
        float v = acc + (bias ? bias[o] : 0.f);
        if (sc) v = fmaf(v, sc[o], bnb[o]);
        if (leaky) v = lrelu(v);
        Out[(size_t)b * ldOut + o] = v;
    }
}

extern "C" void kernel_launch(void* const* d_in, const int* in_sizes, int n_in,
                              void* d_out, int out_size, void* d_ws, size_t ws_size,
                              hipStream_t stream) {
    const float* x   = (const float*)d_in[0];
    const float* W1  = (const float*)d_in[1];
    const float* s1  = (const float*)d_in[2];
    const float* b1  = (const float*)d_in[3];
    const float* W2  = (const float*)d_in[4];
    const float* s2  = (const float*)d_in[5];
    const float* b2  = (const float*)d_in[6];
    const float* W3  = (const float*)d_in[7];
    const float* s3  = (const float*)d_in[8];
    const float* b3  = (const float*)d_in[9];
    const float* W4  = (const float*)d_in[10];
    const float* s4  = (const float*)d_in[11];
    const float* b4  = (const float*)d_in[12];
    const float* W5  = (const float*)d_in[13];
    const float* s5  = (const float*)d_in[14];
    const float* b5  = (const float*)d_in[15];
    const float* L1w = (const float*)d_in[16];
    const float* s6  = (const float*)d_in[17];
    const float* b6  = (const float*)d_in[18];
    const float* L2w = (const float*)d_in[19];
    const float* L2b = (const float*)d_in[20];
    const float* s7  = (const float*)d_in[21];
    const float* b7  = (const float*)d_in[22];
    const float* L3w = (const float*)d_in[23];
    const float* L3b = (const float*)d_in[24];
    const float* F1w = (const float*)d_in[25];
    const float* s8  = (const float*)d_in[26];
    const float* b8  = (const float*)d_in[27];
    const float* F2w = (const float*)d_in[28];
    const float* F2b = (const float*)d_in[29];
    const float* s9  = (const float*)d_in[30];
    const float* b9  = (const float*)d_in[31];
    const float* F3w = (const float*)d_in[32];
    const float* F3b = (const float*)d_in[33];

    float* ws = (float*)d_ws;
    size_t off = 0;
    auto alloc = [&](size_t n) { float* p = ws + off; off += n; return p; };
    float* pts  = alloc((size_t)Bn * Np * 4);
    float* x1   = alloc((size_t)Bn * Np * 64);
    float* x2   = alloc((size_t)Bn * Np * 64);
    float* x3   = alloc((size_t)Bn * Np * 128);
    float* x4   = alloc((size_t)Bn * Np * 256);
    float* xcm  = alloc((size_t)Bn * Np * 128);
    float* xxb  = alloc((size_t)Bn * Np);
    int*   idxb = (int*)alloc((size_t)Bn * Np * Kn);
    float* g0   = alloc((size_t)Bn * 2048);
    float* g1   = alloc((size_t)Bn * 512);
    float* g2   = alloc((size_t)Bn * 256);
    float* y1   = alloc((size_t)Bn * 512);
    float* y2   = alloc((size_t)Bn * 256);
    // alias into xcm (dead after last knn): W5t (512K) + pmax (512K) + psum (512K) <= 2M floats
    float* W5t  = xcm;
    float* pmax = xcm + 524288;
    float* psum = xcm + 1048576;

    k_transpose<<<Bn * Np / 256, 256, 0, stream>>>(x, pts);

    // Layer 1: C=3 (cm = input x directly)
    k_xx<<<Bn * Np / 4, 256, 0, stream>>>(pts, xxb, 3, 4);
    k_knn<3><<<Bn * Np / 4, 256, 0, stream>>>(x, pts, 4, xxb, idxb);
    k_edgeconv<3, 4, 64, 1, 8, 4><<<Bn * Np / 4, 256, 0, stream>>>(pts, idxb, W1, s1, b1, x1, xcm, 1);

    // Layer 2: C=64 -> O=64
    k_xx<<<Bn * Np / 4, 256, 0, stream>>>(x1, xxb, 64, 64);
    k_knn<64><<<Bn * Np / 4, 256, 0, stream>>>(xcm, x1, 64, xxb, idxb);
    k_edgeconv<64, 64, 64, 4, 2, 2><<<Bn * Np / 2, 256, 0, stream>>>(x1, idxb, W2, s2, b2, x2, xcm, 1);

    // Layer 3: C=64 -> O=128
    k_xx<<<Bn * Np / 4, 256, 0, stream>>>(x2, xxb, 64, 64);
    k_knn<64><<<Bn * Np / 4, 256, 0, stream>>>(xcm, x2, 64, xxb, idxb);
    k_edgeconv<64, 64, 128, 8, 2, 2><<<Bn * Np / 2, 256, 0, stream>>>(x2, idxb, W3, s3, b3, x3, xcm, 1);

    // Layer 4: C=128 -> O=256
    k_xx<<<Bn * Np / 4, 256, 0, stream>>>(x3, xxb, 128, 128);
    k_knn<128><<<Bn * Np / 4, 256, 0, stream>>>(xcm, x3, 128, xxb, idxb);
    // xcm is dead from here; W5t/pmax/psum alias it
    k_w5t<<<512, 256, 0, stream>>>(W5, W5t);
    k_edgeconv<128, 128, 256, 8, 4, 2><<<Bn * Np / 2, 256, 0, stream>>>(x3, idxb, W4, s4, b4, x4, nullptr, 0);

    // W5 + pooling (atomic-free)
    k_w5pool<<<Bn * 64, 256, 0, stream>>>(x1, x2, x3, x4, W5t, s5, b5, pmax, psum);
    k_poolred<<<Bn * 1024 / 256, 256, 0, stream>>>(pmax, psum, g0);

    float* out = (float*)d_out;
    // g branch (output 0)
    k_fc<<<dim3(128, Bn), 256, 0, stream>>>(g0, 2048, 2048, L1w, nullptr, s6, b6, 1, g1, 512, 512);
    k_fc<<<dim3(64, Bn), 256, 0, stream>>>(g1, 512, 512, L2w, L2b, s7, b7, 1, g2, 256, 256);
    k_fc<<<dim3(2, Bn), 256, 0, stream>>>(g2, 256, 256, L3w, L3b, nullptr, nullptr, 0, out, 5, 5);
    // y branch (output 1) — uses max half of g0
    k_fc<<<dim3(128, Bn), 256, 0, stream>>>(g0, 2048, 1024, F1w, nullptr, s8, b8, 1, y1, 512, 512);
    k_fc<<<dim3(64, Bn), 256, 0, stream>>>(y1, 512, 512, F2w, F2b, s9, b9, 1, y2, 256, 256);
    k_fc<<<dim3(2, Bn), 256, 0, stream>>>(y2, 256, 256, F3w, F3b, nullptr, nullptr, 0, out + 40, 5, 5);
}

// Round 3
// 2149.415 us; speedup vs baseline: 2.1948x; 2.1948x over previous
//
#include <hip/hip_runtime.h>
#include <math.h>

constexpr int Bn = 8;
constexpr int Np = 2048;
constexpr int Kn = 32;
constexpr float NEGS = 0.2f;

__device__ __forceinline__ float lrelu(float v) { return v > 0.f ? v : NEGS * v; }

// x [B,3,N] -> pts point-major [B*N, 4] (pad lane = 0)
__global__ __launch_bounds__(256) void k_transpose(const float* __restrict__ x, float* __restrict__ pts) {
    int i = blockIdx.x * 256 + threadIdx.x;
    int b = i / Np, n = i % Np;
    float p0 = x[((size_t)b * 3 + 0) * Np + n];
    float p1 = x[((size_t)b * 3 + 1) * Np + n];
    float p2 = x[((size_t)b * 3 + 2) * Np + n];
    float4 v = make_float4(p0, p1, p2, 0.f);
    *(float4*)&pts[(size_t)i * 4] = v;
}

// xx[i] = sum_c pm[i*ld+c]^2 ; one wave per point, 4 points per block
__global__ __launch_bounds__(256) void k_xx(const float* __restrict__ pm, float* __restrict__ xxg, int C, int ld) {
    int wid = threadIdx.x >> 6, lane = threadIdx.x & 63;
    int pt = blockIdx.x * 4 + wid;
    const float* row = pm + (size_t)pt * ld;
    float acc = 0.f;
    for (int c = lane; c < C; c += 64) { float v = row[c]; acc = fmaf(v, v, acc); }
    #pragma unroll
    for (int off = 32; off; off >>= 1) acc += __shfl_down(acc, off, 64);
    if (lane == 0) xxg[pt] = acc;
}

// kNN top-32 (largest of d = 2*inner - xx_n - xx_m). 4 rows per block.
template<int C>
__global__ __launch_bounds__(256) void k_knn(const float* __restrict__ Xcm, const float* __restrict__ Xpm, int ld,
                                             const float* __restrict__ xxg, int* __restrict__ idxo) {
    __shared__ float pcs[4][C];
    __shared__ float dl[4 * Np];
    int blk = blockIdx.x;
    int b = blk / (Np / 4);
    int n0 = (blk % (Np / 4)) * 4;
    int t = threadIdx.x;
    for (int e = t; e < 4 * C; e += 256) {
        int r = e / C, c = e % C;
        pcs[r][c] = Xpm[((size_t)b * Np + n0 + r) * ld + c];
    }
    __syncthreads();
    float dot[4][8] = {};
    for (int c = 0; c < C; ++c) {
        float p0 = pcs[0][c], p1 = pcs[1][c], p2 = pcs[2][c], p3 = pcs[3][c];
        const float* xrow = Xcm + ((size_t)b * C + c) * Np;
        #pragma unroll
        for (int j = 0; j < 8; ++j) {
            float xm = xrow[t + 256 * j];
            dot[0][j] = fmaf(p0, xm, dot[0][j]);
            dot[1][j] = fmaf(p1, xm, dot[1][j]);
            dot[2][j] = fmaf(p2, xm, dot[2][j]);
            dot[3][j] = fmaf(p3, xm, dot[3][j]);
        }
    }
    float xc0 = xxg[b * Np + n0 + 0], xc1 = xxg[b * Np + n0 + 1];
    float xc2 = xxg[b * Np + n0 + 2], xc3 = xxg[b * Np + n0 + 3];
    #pragma unroll
    for (int j = 0; j < 8; ++j) {
        int m = t + 256 * j;
        float xm = xxg[b * Np + m];
        dl[0 * Np + m] = 2.f * dot[0][j] - xc0 - xm;
        dl[1 * Np + m] = 2.f * dot[1][j] - xc1 - xm;
        dl[2 * Np + m] = 2.f * dot[2][j] - xc2 - xm;
        dl[3 * Np + m] = 2.f * dot[3][j] - xc3 - xm;
    }
    __syncthreads();
    int w = t >> 6, lane = t & 63;
    float v[32];
    #pragma unroll
    for (int j = 0; j < 32; ++j) v[j] = dl[w * Np + lane + 64 * j];
    size_t ob = ((size_t)b * Np + n0 + w) * Kn;
    for (int it = 0; it < Kn; ++it) {
        float bv = v[0]; int bj = 0;
        #pragma unroll
        for (int j = 1; j < 32; ++j) if (v[j] > bv) { bv = v[j]; bj = j; }
        int bm = lane + 64 * bj;
        #pragma unroll
        for (int off = 32; off; off >>= 1) {
            float ov = __shfl_down(bv, off, 64);
            int om = __shfl_down(bm, off, 64);
            if (ov > bv || (ov == bv && om < bm)) { bv = ov; bm = om; }
        }
        bm = __shfl(bm, 0, 64);
        if ((bm & 63) == lane) v[bm >> 6] = -INFINITY;
        if (lane == 0) idxo[ob + it] = bm;
    }
}

// W split+scale+transpose: WnsT[c][o] = W[o][c]*s[o]; WdsT[c][o] = (W[o][C+c]-W[o][c])*s[o]
__global__ __launch_bounds__(256) void k_wsplit(const float* __restrict__ W, const float* __restrict__ s,
                                                int C, int O, float* __restrict__ WnsT, float* __restrict__ WdsT) {
    int i = blockIdx.x * 256 + threadIdx.x;
    if (i >= C * O) return;
    int c = i / O, o = i % O;
    float a = W[(size_t)o * 2 * C + c];
    float q = W[(size_t)o * 2 * C + C + c];
    float sv = s[o];
    WnsT[i] = a * sv;
    WdsT[i] = (q - a) * sv;
}

// cb[n][o] = sum_c ctr[n][c]*WdsT[c][o] + b[o].  32 points per block.
template<int C, int O, int OPT>
__global__ __launch_bounds__(256) void k_ctr(const float* __restrict__ Xpm, const float* __restrict__ WdsT,
                                             const float* __restrict__ bg, float* __restrict__ cb) {
    constexpr int OG = O / OPT, MG = 256 / OG, MPT = 32 / MG;
    constexpr int C4 = C / 4;
    __shared__ float xs[32][C];
    int b = blockIdx.x / (Np / 32);
    int n0 = (blockIdx.x % (Np / 32)) * 32;
    int t = threadIdx.x;
    const float4* Xp4 = (const float4*)Xpm;
    for (int e = t; e < 32 * C4; e += 256) {
        int pt = e / C4, c4 = e % C4;
        *(float4*)&xs[pt][4 * c4] = Xp4[((size_t)b * Np + n0 + pt) * C4 + c4];
    }
    __syncthreads();
    int og = t % OG, mg = t / OG;
    int o0 = og * OPT;
    float acc[MPT][OPT] = {};
    for (int c = 0; c < C; ++c) {
        float wv[OPT];
        #pragma unroll
        for (int p4 = 0; p4 < OPT / 4; ++p4)
            *(float4*)&wv[4 * p4] = *(const float4*)&WdsT[(size_t)c * O + o0 + 4 * p4];
        #pragma unroll
        for (int m = 0; m < MPT; ++m) {
            float xv = xs[mg * MPT + m][c];
            #pragma unroll
            for (int p = 0; p < OPT; ++p) acc[m][p] = fmaf(wv[p], xv, acc[m][p]);
        }
    }
    #pragma unroll
    for (int m = 0; m < MPT; ++m) {
        #pragma unroll
        for (int p = 0; p < OPT; ++p) {
            int o = o0 + p;
            cb[((size_t)b * Np + n0 + mg * MPT + m) * O + o] = acc[m][p] + bg[o];
        }
    }
}

// Main EdgeConv GEMM: M=PTS*32 gathered rows x O outputs, K=C. W streamed [c][o] (transposed,
// scaled); nbr in LDS read as wave-broadcast b128; cb added at epilogue; max over k then lrelu.
// cb may alias Ypm (per-element read-then-write by owning thread).
template<int C, int O, int PTS, int OPT>
__global__ __launch_bounds__(256) void k_ec2(const float* __restrict__ Xpm, const int* __restrict__ idxg,
                                             const float* __restrict__ WnsT, const float* __restrict__ cb,
                                             float* __restrict__ Ypm, float* __restrict__ Ycm, int wcm) {
    constexpr int M = PTS * 32, OG = O / OPT, MG = 256 / OG, MPT = M / MG, GPP = MG / PTS;
    constexpr int C4 = C / 4;
    __shared__ float nbr[M][C];
    __shared__ float red[PTS][GPP][O];
    int b = blockIdx.x / (Np / PTS);
    int n0 = (blockIdx.x % (Np / PTS)) * PTS;
    int t = threadIdx.x;
    const int* ip = idxg + ((size_t)b * Np + n0) * Kn;
    const float4* Xp4 = (const float4*)Xpm;
    for (int e = t; e < M * C4; e += 256) {
        int row = e / C4, c4 = e % C4;
        int pt = row >> 5, k = row & 31;
        int nb = ip[pt * Kn + k];
        *(float4*)&nbr[row][4 * c4] = Xp4[((size_t)b * Np + nb) * C4 + c4];
    }
    __syncthreads();
    int og = t % OG, mg = t / OG;
    int o0 = og * OPT, r0 = mg * MPT;
    float acc[MPT][OPT] = {};
    for (int c0 = 0; c0 < C; c0 += 4) {
        float wv[4][OPT];
        #pragma unroll
        for (int cc = 0; cc < 4; ++cc) {
            #pragma unroll
            for (int p4 = 0; p4 < OPT / 4; ++p4)
                *(float4*)&wv[cc][4 * p4] = *(const float4*)&WnsT[(size_t)(c0 + cc) * O + o0 + 4 * p4];
        }
        #pragma unroll
        for (int m = 0; m < MPT; ++m) {
            float4 nv = *(const float4*)&nbr[r0 + m][c0];
            #pragma unroll
            for (int p = 0; p < OPT; ++p) {
                acc[m][p] = fmaf(wv[0][p], nv.x, acc[m][p]);
                acc[m][p] = fmaf(wv[1][p], nv.y, acc[m][p]);
                acc[m][p] = fmaf(wv[2][p], nv.z, acc[m][p]);
                acc[m][p] = fmaf(wv[3][p], nv.w, acc[m][p]);
            }
        }
    }
    // per-thread max over its MPT rows (all same pt)
    int pt = r0 >> 5;
    int gi = mg % GPP;
    #pragma unroll
    for (int p = 0; p < OPT; ++p) {
        float m = acc[0][p];
        #pragma unroll
        for (int mm = 1; mm < MPT; ++mm) m = fmaxf(m, acc[mm][p]);
        red[pt][gi][o0 + p] = m;
    }
    __syncthreads();
    for (int idx = t; idx < PTS * O; idx += 256) {
        int pp = idx / O, o = idx % O;
        float m = red[pp][0][o];
        #pragma unroll
        for (int g = 1; g < GPP; ++g) m = fmaxf(m, red[pp][g][o]);
        size_t ni = (size_t)b * Np + n0 + pp;
        float v = lrelu(m + cb[ni * O + o]);
        Ypm[ni * O + o] = v;
        if (wcm) Ycm[((size_t)b * O + o) * Np + n0 + pp] = v;
    }
}

// Legacy fused EdgeConv for layer 1 (C=3): tiny W, all-in-one.
template<int C, int CPAD, int O, int OPT, int KPT, int PTS>
__global__ __launch_bounds__(256) void k_edgeconv(
    const float* __restrict__ Xpm, const int* __restrict__ idxg,
    const float* __restrict__ W, const float* __restrict__ sg, const float* __restrict__ bg,
    float* __restrict__ Ypm, float* __restrict__ Ycm, int wcm)
{
    constexpr int OG = O / OPT;
    constexpr int NKG = 256 / OG;
    constexpr int CL = CPAD + 4;
    static_assert(NKG * KPT == Kn, "k mapping");
    __shared__ float nbr[PTS][Kn][CL];
    __shared__ float ctr[PTS][CPAD];
    __shared__ float red[PTS][OPT][4][OG];
    int blk = blockIdx.x;
    int b = blk / (Np / PTS);
    int n0 = (blk % (Np / PTS)) * PTS;
    int t = threadIdx.x;
    int lane = t & 63, wid = t >> 6;
    const int* ip = idxg + ((size_t)b * Np + n0) * Kn;
    const float4* Xp4 = (const float4*)Xpm;
    constexpr int C4 = CPAD / 4;
    for (int e = t; e < PTS * C4; e += 256) {
        int pt = e / C4, c4 = e % C4;
        *(float4*)&ctr[pt][4 * c4] = Xp4[((size_t)b * Np + n0 + pt) * C4 + c4];
    }
    for (int e = t; e < PTS * Kn * C4; e += 256) {
        int pt = e / (Kn * C4);
        int r = e % (Kn * C4);
        int k = r / C4, c4 = r % C4;
        int nb = ip[pt * Kn + k];
        *(float4*)&nbr[pt][k][4 * c4] = Xp4[((size_t)b * Np + nb) * C4 + c4];
    }
    __syncthreads();
    int og = t % OG, kg = t / OG;
    float acc[PTS][OPT][KPT] = {};
    float ctt[PTS][OPT] = {};
    for (int c0 = 0; c0 < CPAD; c0 += 4) {
        float wn[OPT][4], wd[OPT][4];
        #pragma unroll
        for (int p = 0; p < OPT; ++p) {
            #pragma unroll
            for (int cc = 0; cc < 4; ++cc) {
                int c = c0 + cc;
                float a = (c < C) ? W[(size_t)(og + p * OG) * (2 * C) + c] : 0.f;
                float q = (c < C) ? W[(size_t)(og + p * OG) * (2 * C) + C + c] : 0.f;
                wn[p][cc] = a; wd[p][cc] = q - a;
            }
        }
        #pragma unroll
        for (int pt = 0; pt < PTS; ++pt) {
            float4 cv = *(const float4*)&ctr[pt][c0];
            #pragma unroll
            for (int p = 0; p < OPT; ++p) {
                ctt[pt][p] = fmaf(wd[p][0], cv.x, ctt[pt][p]);
                ctt[pt][p] = fmaf(wd[p][1], cv.y, ctt[pt][p]);
                ctt[pt][p] = fmaf(wd[p][2], cv.z, ctt[pt][p]);
                ctt[pt][p] = fmaf(wd[p][3], cv.w, ctt[pt][p]);
            }
        }
        #pragma unroll
        for (int pt = 0; pt < PTS; ++pt) {
            #pragma unroll
            for (int k = 0; k < KPT; ++k) {
                float4 nv = *(const float4*)&nbr[pt][kg * KPT + k][c0];
                #pragma unroll
                for (int p = 0; p < OPT; ++p) {
                    acc[pt][p][k] = fmaf(wn[p][0], nv.x, acc[pt][p][k]);
                    acc[pt][p][k] = fmaf(wn[p][1], nv.y, acc[pt][p][k]);
                    acc[pt][p][k] = fmaf(wn[p][2], nv.z, acc[pt][p][k]);
                    acc[pt][p][k] = fmaf(wn[p][3], nv.w, acc[pt][p][k]);
                }
            }
        }
    }
    #pragma unroll
    for (int pt = 0; pt < PTS; ++pt) {
        #pragma unroll
        for (int p = 0; p < OPT; ++p) {
            int o = og + p * OG;
            float sv = sg[o], bv = bg[o];
            float m = -INFINITY;
            #pragma unroll
            for (int k = 0; k < KPT; ++k) {
                float hv = fmaf(acc[pt][p][k] + ctt[pt][p], sv, bv);
                m = fmaxf(m, lrelu(hv));
            }
            #pragma unroll
            for (int s = OG; s < 64; s <<= 1) m = fmaxf(m, __shfl_xor(m, s, 64));
            if (lane < OG) red[pt][p][wid][lane] = m;
        }
    }
    __syncthreads();
    if (t < OG) {
        #pragma unroll
        for (int pt = 0; pt < PTS; ++pt) {
            #pragma unroll
            for (int p = 0; p < OPT; ++p) {
                float m = fmaxf(fmaxf(red[pt][p][0][t], red[pt][p][1][t]),
                                fmaxf(red[pt][p][2][t], red[pt][p][3][t]));
                int o = t + p * OG;
                Ypm[((size_t)b * Np + n0 + pt) * O + o] = m;
                if (wcm) Ycm[((size_t)b * O + o) * Np + n0 + pt] = m;
            }
        }
    }
}

// W5 transpose [1024][512] -> [512][1024] (32x32 LDS tiles)
__global__ __launch_bounds__(256) void k_w5t(const float* __restrict__ W5, float* __restrict__ W5t) {
    __shared__ float tile[32][33];
    int o0 = (blockIdx.x & 31) * 32;
    int c0 = (blockIdx.x >> 5) * 32;
    int lr = threadIdx.x >> 5, lc = threadIdx.x & 31;
    #pragma unroll
    for (int j = 0; j < 4; ++j) {
        int r = lr + 8 * j;
        tile[r][lc] = W5[(size_t)(o0 + r) * 512 + c0 + lc];
    }
    __syncthreads();
    #pragma unroll
    for (int j = 0; j < 4; ++j) {
        int r = lr + 8 * j;
        W5t[(size_t)(c0 + r) * 1024 + o0 + lc] = tile[lc][r];
    }
}

// W5 (channel-major W5t) + BN + LeakyReLU + per-block max/sum over 32 points -> partials.
__global__ __launch_bounds__(256) void k_w5pool(
    const float* __restrict__ x1, const float* __restrict__ x2,
    const float* __restrict__ x3, const float* __restrict__ x4,
    const float* __restrict__ W5t, const float* __restrict__ s5, const float* __restrict__ b5,
    float* __restrict__ pmax, float* __restrict__ psum)
{
    constexpr int PP = 16;
    __shared__ float cat[PP][512];
    int blk = blockIdx.x;
    int b = blk >> 6;
    int chunk = blk & 63;
    int n0 = chunk * 32;
    int t = threadIdx.x;
    float mx[4] = {-INFINITY, -INFINITY, -INFINITY, -INFINITY};
    float sm[4] = {};
    for (int pass = 0; pass < 2; ++pass) {
        __syncthreads();
        for (int e = t; e < PP * 128; e += 256) {
            int pt = e >> 7, c4 = e & 127;
            size_t pi = (size_t)b * Np + n0 + pass * PP + pt;
            float4 v;
            if (c4 < 16)      v = ((const float4*)x1)[pi * 16 + c4];
            else if (c4 < 32) v = ((const float4*)x2)[pi * 16 + (c4 - 16)];
            else if (c4 < 64) v = ((const float4*)x3)[pi * 32 + (c4 - 32)];
            else              v = ((const float4*)x4)[pi * 64 + (c4 - 64)];
            *(float4*)&cat[pt][4 * c4] = v;
        }
        __syncthreads();
        float acc[4][PP] = {};
        for (int c0 = 0; c0 < 512; c0 += 4) {
            float wv[4][4];
            #pragma unroll
            for (int j = 0; j < 4; ++j) {
                const float* row = W5t + (size_t)(c0 + j) * 1024 + t;
                #pragma unroll
                for (int r = 0; r < 4; ++r) wv[j][r] = row[256 * r];
            }
            #pragma unroll
            for (int pt = 0; pt < PP; ++pt) {
                float4 cv = *(const float4*)&cat[pt][c0];
                #pragma unroll
                for (int r = 0; r < 4; ++r) {
                    acc[r][pt] = fmaf(wv[0][r], cv.x, acc[r][pt]);
                    acc[r][pt] = fmaf(wv[1][r], cv.y, acc[r][pt]);
                    acc[r][pt] = fmaf(wv[2][r], cv.z, acc[r][pt]);
                    acc[r][pt] = fmaf(wv[3][r], cv.w, acc[r][pt]);
                }
            }
        }
        #pragma unroll
        for (int r = 0; r < 4; ++r) {
            int o = t + 256 * r;
            float sv = s5[o], bv = b5[o];
            #pragma unroll
            for (int pt = 0; pt < PP; ++pt) {
                float v = lrelu(fmaf(acc[r][pt], sv, bv));
                mx[r] = fmaxf(mx[r], v);
                sm[r] += v;
            }
        }
    }
    #pragma unroll
    for (int r = 0; r < 4; ++r) {
        int o = t + 256 * r;
        pmax[((size_t)(b * 64 + chunk)) * 1024 + o] = mx[r];
        psum[((size_t)(b * 64 + chunk)) * 1024 + o] = sm[r];
    }
}

__global__ __launch_bounds__(256) void k_poolred(const float* __restrict__ pmax, const float* __restrict__ psum,
                                                 float* __restrict__ g0) {
    int i = blockIdx.x * 256 + threadIdx.x;
    int b = i >> 10, o = i & 1023;
    float mx = -INFINITY, sm = 0.f;
    for (int ch = 0; ch < 64; ++ch) {
        size_t idx = ((size_t)(b * 64 + ch)) * 1024 + o;
        mx = fmaxf(mx, pmax[idx]);
        sm += psum[idx];
    }
    g0[(size_t)b * 2048 + o] = mx;
    g0[(size_t)b * 2048 + 1024 + o] = sm * (1.f / Np);
}

__global__ __launch_bounds__(256) void k_fc(const float* __restrict__ In, int ldIn, int C,
                                            const float* __restrict__ Wm,
                                            const float* __restrict__ bias,
                                            const float* __restrict__ sc, const float* __restrict__ bnb,
                                            int leaky, float* __restrict__ Out, int ldOut, int O) {
    int wid = threadIdx.x >> 6, lane = threadIdx.x & 63;
    int o = blockIdx.x * 4 + wid;
    int b = blockIdx.y;
    if (o >= O) return;
    const float* in = In + (size_t)b * ldIn;
    const float* wr = Wm + (size_t)o * C;
    float acc = 0.f;
    for (int c = lane; c < C; c += 64) acc = fmaf(in[c], wr[c], acc);
    #pragma unroll
    for (int off = 32; off; off >>= 1) acc += __shfl_down(acc, off, 64);
    if (lane == 0) {
        float v = acc + (bias ? bias[o] : 0.f);
        if (sc) v = fmaf(v, sc[o], bnb[o]);
        if (leaky) v = lrelu(v);
        Out[(size_t)b * ldOut + o] = v;
    }
}

extern "C" void kernel_launch(void* const* d_in, const int* in_sizes, int n_in,
                              void* d_out, int out_size, void* d_ws, size_t ws_size,
                              hipStream_t stream) {
    const float* x   = (const float*)d_in[0];
    const float* W1  = (const float*)d_in[1];
    const float* s1  = (const float*)d_in[2];
    const float* b1  = (const float*)d_in[3];
    const float* W2  = (const float*)d_in[4];
    const float* s2  = (const float*)d_in[5];
    const float* b2  = (const float*)d_in[6];
    const float* W3  = (const float*)d_in[7];
    const float* s3  = (const float*)d_in[8];
    const float* b3  = (const float*)d_in[9];
    const float* W4  = (const float*)d_in[10];
    const float* s4  = (const float*)d_in[11];
    const float* b4  = (const float*)d_in[12];
    const float* W5  = (const float*)d_in[13];
    const float* s5  = (const float*)d_in[14];
    const float* b5  = (const float*)d_in[15];
    const float* L1w = (const float*)d_in[16];
    const float* s6  = (const float*)d_in[17];
    const float* b6  = (const float*)d_in[18];
    const float* L2w = (const float*)d_in[19];
    const float* L2b = (const float*)d_in[20];
    const float* s7  = (const float*)d_in[21];
    const float* b7  = (const float*)d_in[22];
    const float* L3w = (const float*)d_in[23];
    const float* L3b = (const float*)d_in[24];
    const float* F1w = (const float*)d_in[25];
    const float* s8  = (const float*)d_in[26];
    const float* b8  = (const float*)d_in[27];
    const float* F2w = (const float*)d_in[28];
    const float* F2b = (const float*)d_in[29];
    const float* s9  = (const float*)d_in[30];
    const float* b9  = (const float*)d_in[31];
    const float* F3w = (const float*)d_in[32];
    const float* F3b = (const float*)d_in[33];

    float* ws = (float*)d_ws;
    size_t off = 0;
    auto alloc = [&](size_t n) { float* p = ws + off; off += n; return p; };
    float* pts  = alloc((size_t)Bn * Np * 4);
    float* x1   = alloc((size_t)Bn * Np * 64);
    float* x2   = alloc((size_t)Bn * Np * 64);
    float* x3   = alloc((size_t)Bn * Np * 128);
    float* x4   = alloc((size_t)Bn * Np * 256);
    float* xcm  = alloc((size_t)Bn * Np * 128);
    float* xxb  = alloc((size_t)Bn * Np);
    int*   idxb = (int*)alloc((size_t)Bn * Np * Kn);
    float* g0   = alloc((size_t)Bn * 2048);
    float* g1   = alloc((size_t)Bn * 512);
    float* g2   = alloc((size_t)Bn * 256);
    float* y1   = alloc((size_t)Bn * 512);
    float* y2   = alloc((size_t)Bn * 256);
    float* WnsT2 = alloc(64 * 64);
    float* WdsT2 = alloc(64 * 64);
    float* WnsT3 = alloc(64 * 128);
    float* WdsT3 = alloc(64 * 128);
    float* WnsT4 = alloc(128 * 256);
    float* WdsT4 = alloc(128 * 256);
    // alias into xcm (dead after last knn): W5t (512K) + pmax (512K) + psum (512K)
    float* W5t  = xcm;
    float* pmax = xcm + 524288;
    float* psum = xcm + 1048576;
    // cb buffers alias the layer outputs (read-then-write per element)
    float* cb2 = x2;
    float* cb3 = x3;
    float* cb4 = x4;

    k_transpose<<<Bn * Np / 256, 256, 0, stream>>>(x, pts);
    k_wsplit<<<16, 256, 0, stream>>>(W2, s2, 64, 64, WnsT2, WdsT2);
    k_wsplit<<<32, 256, 0, stream>>>(W3, s3, 64, 128, WnsT3, WdsT3);
    k_wsplit<<<128, 256, 0, stream>>>(W4, s4, 128, 256, WnsT4, WdsT4);

    // Layer 1: C=3 (cm = input x directly)
    k_xx<<<Bn * Np / 4, 256, 0, stream>>>(pts, xxb, 3, 4);
    k_knn<3><<<Bn * Np / 4, 256, 0, stream>>>(x, pts, 4, xxb, idxb);
    k_edgeconv<3, 4, 64, 1, 8, 4><<<Bn * Np / 4, 256, 0, stream>>>(pts, idxb, W1, s1, b1, x1, xcm, 1);

    // Layer 2: C=64 -> O=64
    k_xx<<<Bn * Np / 4, 256, 0, stream>>>(x1, xxb, 64, 64);
    k_knn<64><<<Bn * Np / 4, 256, 0, stream>>>(xcm, x1, 64, xxb, idxb);
    k_ctr<64, 64, 4><<<Bn * Np / 32, 256, 0, stream>>>(x1, WdsT2, b2, cb2);
    k_ec2<64, 64, 4, 4><<<Bn * Np / 4, 256, 0, stream>>>(x1, idxb, WnsT2, cb2, x2, xcm, 1);

    // Layer 3: C=64 -> O=128
    k_xx<<<Bn * Np / 4, 256, 0, stream>>>(x2, xxb, 64, 64);
    k_knn<64><<<Bn * Np / 4, 256, 0, stream>>>(xcm, x2, 64, xxb, idxb);
    k_ctr<64, 128, 8><<<Bn * Np / 32, 256, 0, stream>>>(x2, WdsT3, b3, cb3);
    k_ec2<64, 128, 2, 8><<<Bn * Np / 2, 256, 0, stream>>>(x2, idxb, WnsT3, cb3, x3, xcm, 1);

    // Layer 4: C=128 -> O=256
    k_xx<<<Bn * Np / 4, 256, 0, stream>>>(x3, xxb, 128, 128);
    k_knn<128><<<Bn * Np / 4, 256, 0, stream>>>(xcm, x3, 128, xxb, idxb);
    // xcm dead from here; W5t/pmax/psum alias it
    k_w5t<<<512, 256, 0, stream>>>(W5, W5t);
    k_ctr<128, 256, 8><<<Bn * Np / 32, 256, 0, stream>>>(x3, WdsT4, b4, cb4);
    k_ec2<128, 256, 2, 8><<<Bn * Np / 2, 256, 0, stream>>>(x3, idxb, WnsT4, cb4, x4, nullptr, 0);

    // W5 + pooling (atomic-free)
    k_w5pool<<<Bn * 64, 256, 0, stream>>>(x1, x2, x3, x4, W5t, s5, b5, pmax, psum);
    k_poolred<<<Bn * 1024 / 256, 256, 0, stream>>>(pmax, psum, g0);

    float* out = (float*)d_out;
    k_fc<<<dim3(128, Bn), 256, 0, stream>>>(g0, 2048, 2048, L1w, nullptr, s6, b6, 1, g1, 512, 512);
    k_fc<<<dim3(64, Bn), 256, 0, stream>>>(g1, 512, 512, L2w, L2b, s7, b7, 1, g2, 256, 256);
    k_fc<<<dim3(2, Bn), 256, 0, stream>>>(g2, 256, 256, L3w, L3b, nullptr, nullptr, 0, out, 5, 5);
    k_fc<<<dim3(128, Bn), 256, 0, stream>>>(g0, 2048, 1024, F1w, nullptr, s8, b8, 1, y1, 512, 512);
    k_fc<<<dim3(64, Bn), 256, 0, stream>>>(y1, 512, 512, F2w, F2b, s9, b9, 1, y2, 256, 256);
    k_fc<<<dim3(2, Bn), 256, 0, stream>>>(y2, 256, 256, F3w, F3b, nullptr, nullptr, 0, out + 40, 5, 5);
}

// Round 4
// 1851.151 us; speedup vs baseline: 2.5484x; 1.1611x over previous
//
#include <hip/hip_runtime.h>
#include <math.h>

constexpr int Bn = 8;
constexpr int Np = 2048;
constexpr int Kn = 32;
constexpr float NEGS = 0.2f;

typedef __attribute__((ext_vector_type(8))) short short8;
typedef __attribute__((ext_vector_type(4))) float f32x4;
typedef unsigned short ushortT;

__device__ __forceinline__ float lrelu(float v) { return v > 0.f ? v : NEGS * v; }

// split fp32 -> bf16 hi (truncate) + bf16 lo (residual, truncate); packed 2-at-a-time
__device__ __forceinline__ void cvt2u(float a, float b, unsigned& h, unsigned& l) {
    unsigned ua = __float_as_uint(a), ub = __float_as_uint(b);
    h = (ua >> 16) | (ub & 0xffff0000u);
    float ra = a - __uint_as_float(ua & 0xffff0000u);
    float rb = b - __uint_as_float(ub & 0xffff0000u);
    l = (__float_as_uint(ra) >> 16) | (__float_as_uint(rb) & 0xffff0000u);
}

// x [B,3,N] -> pts point-major [B*N, 4] (pad lane = 0)
__global__ __launch_bounds__(256) void k_transpose(const float* __restrict__ x, float* __restrict__ pts) {
    int i = blockIdx.x * 256 + threadIdx.x;
    int b = i / Np, n = i % Np;
    float p0 = x[((size_t)b * 3 + 0) * Np + n];
    float p1 = x[((size_t)b * 3 + 1) * Np + n];
    float p2 = x[((size_t)b * 3 + 2) * Np + n];
    float4 v = make_float4(p0, p1, p2, 0.f);
    *(float4*)&pts[(size_t)i * 4] = v;
}

// xx[i] = sum_c pm[i*ld+c]^2 ; one wave per point, 4 points per block
__global__ __launch_bounds__(256) void k_xx(const float* __restrict__ pm, float* __restrict__ xxg, int C, int ld) {
    int wid = threadIdx.x >> 6, lane = threadIdx.x & 63;
    int pt = blockIdx.x * 4 + wid;
    const float* row = pm + (size_t)pt * ld;
    float acc = 0.f;
    for (int c = lane; c < C; c += 64) { float v = row[c]; acc = fmaf(v, v, acc); }
    #pragma unroll
    for (int off = 32; off; off >>= 1) acc += __shfl_down(acc, off, 64);
    if (lane == 0) xxg[pt] = acc;
}

// kNN top-32 (largest of d = 2*inner - xx_n - xx_m). 4 rows per block.
template<int C>
__global__ __launch_bounds__(256) void k_knn(const float* __restrict__ Xcm, const float* __restrict__ Xpm, int ld,
                                             const float* __restrict__ xxg, int* __restrict__ idxo) {
    __shared__ float pcs[4][C];
    __shared__ float dl[4 * Np];
    int blk = blockIdx.x;
    int b = blk / (Np / 4);
    int n0 = (blk % (Np / 4)) * 4;
    int t = threadIdx.x;
    for (int e = t; e < 4 * C; e += 256) {
        int r = e / C, c = e % C;
        pcs[r][c] = Xpm[((size_t)b * Np + n0 + r) * ld + c];
    }
    __syncthreads();
    float dot[4][8] = {};
    for (int c = 0; c < C; ++c) {
        float p0 = pcs[0][c], p1 = pcs[1][c], p2 = pcs[2][c], p3 = pcs[3][c];
        const float* xrow = Xcm + ((size_t)b * C + c) * Np;
        #pragma unroll
        for (int j = 0; j < 8; ++j) {
            float xm = xrow[t + 256 * j];
            dot[0][j] = fmaf(p0, xm, dot[0][j]);
            dot[1][j] = fmaf(p1, xm, dot[1][j]);
            dot[2][j] = fmaf(p2, xm, dot[2][j]);
            dot[3][j] = fmaf(p3, xm, dot[3][j]);
        }
    }
    float xc0 = xxg[b * Np + n0 + 0], xc1 = xxg[b * Np + n0 + 1];
    float xc2 = xxg[b * Np + n0 + 2], xc3 = xxg[b * Np + n0 + 3];
    #pragma unroll
    for (int j = 0; j < 8; ++j) {
        int m = t + 256 * j;
        float xm = xxg[b * Np + m];
        dl[0 * Np + m] = 2.f * dot[0][j] - xc0 - xm;
        dl[1 * Np + m] = 2.f * dot[1][j] - xc1 - xm;
        dl[2 * Np + m] = 2.f * dot[2][j] - xc2 - xm;
        dl[3 * Np + m] = 2.f * dot[3][j] - xc3 - xm;
    }
    __syncthreads();
    int w = t >> 6, lane = t & 63;
    float v[32];
    #pragma unroll
    for (int j = 0; j < 32; ++j) v[j] = dl[w * Np + lane + 64 * j];
    size_t ob = ((size_t)b * Np + n0 + w) * Kn;
    for (int it = 0; it < Kn; ++it) {
        float bv = v[0]; int bj = 0;
        #pragma unroll
        for (int j = 1; j < 32; ++j) if (v[j] > bv) { bv = v[j]; bj = j; }
        int bm = lane + 64 * bj;
        #pragma unroll
        for (int off = 32; off; off >>= 1) {
            float ov = __shfl_down(bv, off, 64);
            int om = __shfl_down(bm, off, 64);
            if (ov > bv || (ov == bv && om < bm)) { bv = ov; bm = om; }
        }
        bm = __shfl(bm, 0, 64);
        if ((bm & 63) == lane) v[bm >> 6] = -INFINITY;
        if (lane == 0) idxo[ob + it] = bm;
    }
}

// W split+scale+transpose (fp32, for k_ctr): WdsT[c][o] = (W[o][C+c]-W[o][c])*s[o]
__global__ __launch_bounds__(256) void k_wsplit(const float* __restrict__ W, const float* __restrict__ s,
                                                int C, int O, float* __restrict__ WnsT, float* __restrict__ WdsT) {
    int i = blockIdx.x * 256 + threadIdx.x;
    if (i >= C * O) return;
    int c = i / O, o = i % O;
    float a = W[(size_t)o * 2 * C + c];
    float q = W[(size_t)o * 2 * C + C + c];
    float sv = s[o];
    WnsT[i] = a * sv;
    WdsT[i] = (q - a) * sv;
}

// Pack neighbor-half of W (scaled) into mfma_16x16x32 B-fragment order, split bf16 hi/lo.
// B[k][o]: lane = ((k>>3)&3)*16 + (o&15), j = k&7, tile (ks=k>>5, nt=o>>4).
__global__ __launch_bounds__(256) void k_wpack(const float* __restrict__ W, const float* __restrict__ s,
                                               int C, int O, ushortT* __restrict__ Bh, ushortT* __restrict__ Bl) {
    int i = blockIdx.x * 256 + threadIdx.x;
    if (i >= C * O) return;
    int k = i / O, o = i % O;
    float v = W[(size_t)o * 2 * C + k] * s[o];
    int ks = k >> 5, quad = (k >> 3) & 3, j = k & 7;
    int nt = o >> 4, lane = quad * 16 + (o & 15);
    int NT = O / 16;
    size_t idx = (((size_t)(ks * NT + nt)) * 64 + lane) * 8 + j;
    unsigned u = __float_as_uint(v);
    Bh[idx] = (ushortT)(u >> 16);
    float r = v - __uint_as_float(u & 0xffff0000u);
    Bl[idx] = (ushortT)(__float_as_uint(r) >> 16);
}

// cb[n][o] = sum_c ctr[n][c]*WdsT[c][o] + b[o].  32 points per block.
template<int C, int O, int OPT>
__global__ __launch_bounds__(256) void k_ctr(const float* __restrict__ Xpm, const float* __restrict__ WdsT,
                                             const float* __restrict__ bg, float* __restrict__ cb) {
    constexpr int OG = O / OPT, MG = 256 / OG, MPT = 32 / MG;
    constexpr int C4 = C / 4;
    __shared__ float xs[32][C];
    int b = blockIdx.x / (Np / 32);
    int n0 = (blockIdx.x % (Np / 32)) * 32;
    int t = threadIdx.x;
    const float4* Xp4 = (const float4*)Xpm;
    for (int e = t; e < 32 * C4; e += 256) {
        int pt = e / C4, c4 = e % C4;
        *(float4*)&xs[pt][4 * c4] = Xp4[((size_t)b * Np + n0 + pt) * C4 + c4];
    }
    __syncthreads();
    int og = t % OG, mg = t / OG;
    int o0 = og * OPT;
    float acc[MPT][OPT] = {};
    for (int c = 0; c < C; ++c) {
        float wv[OPT];
        #pragma unroll
        for (int p4 = 0; p4 < OPT / 4; ++p4)
            *(float4*)&wv[4 * p4] = *(const float4*)&WdsT[(size_t)c * O + o0 + 4 * p4];
        #pragma unroll
        for (int m = 0; m < MPT; ++m) {
            float xv = xs[mg * MPT + m][c];
            #pragma unroll
            for (int p = 0; p < OPT; ++p) acc[m][p] = fmaf(wv[p], xv, acc[m][p]);
        }
    }
    #pragma unroll
    for (int m = 0; m < MPT; ++m) {
        #pragma unroll
        for (int p = 0; p < OPT; ++p) {
            int o = o0 + p;
            cb[((size_t)b * Np + n0 + mg * MPT + m) * O + o] = acc[m][p] + bg[o];
        }
    }
}

// MFMA EdgeConv GEMM: M=64 gathered rows (PTS=2 pts x 32 nbrs) x O outputs, K=C.
// Split-bf16 (hi/lo): 3 mfma_16x16x32 per tile-step, fp32-grade accuracy.
// A in LDS (bf16 hi/lo, row pad +8 ushorts), B pre-packed fragment-order from global.
template<int C, int O, int PTS>
__global__ __launch_bounds__(256) void k_ec3(const float* __restrict__ Xpm, const int* __restrict__ idxg,
                                             const ushortT* __restrict__ Bh, const ushortT* __restrict__ Bl,
                                             const float* __restrict__ cb,
                                             float* __restrict__ Ypm, float* __restrict__ Ycm, int wcm) {
    static_assert(PTS == 2, "M=64 mapping");
    constexpr int M = 64, NT = O / 16, KS = C / 32, C4 = C / 4, CP = C + 8;
    __shared__ ushortT Ah[M][CP];
    __shared__ ushortT Al[M][CP];
    __shared__ float red[PTS][2][O];
    int b = blockIdx.x / (Np / PTS);
    int n0 = (blockIdx.x % (Np / PTS)) * PTS;
    int t = threadIdx.x;
    const int* ip = idxg + ((size_t)b * Np + n0) * Kn;
    const float4* Xp4 = (const float4*)Xpm;
    for (int e = t; e < M * C4; e += 256) {
        int row = e / C4, c4 = e % C4;
        float4 v = Xp4[((size_t)b * Np + ip[row]) * C4 + c4];
        unsigned h0, l0, h1, l1;
        cvt2u(v.x, v.y, h0, l0);
        cvt2u(v.z, v.w, h1, l1);
        *(uint2*)&Ah[row][4 * c4] = make_uint2(h0, h1);
        *(uint2*)&Al[row][4 * c4] = make_uint2(l0, l1);
    }
    __syncthreads();
    int w = t >> 6, lane = t & 63;
    int quad = lane >> 4, col = lane & 15;
    int mrow = w * 16 + col;           // a-frag: A[m=lane&15][k=quad*8+j]
    f32x4 acc[NT];
    #pragma unroll
    for (int nt = 0; nt < NT; ++nt) acc[nt] = (f32x4){0.f, 0.f, 0.f, 0.f};
    for (int ks = 0; ks < KS; ++ks) {
        int kb = ks * 32 + quad * 8;
        short8 ah = *(const short8*)&Ah[mrow][kb];
        short8 al = *(const short8*)&Al[mrow][kb];
        #pragma unroll
        for (int nt = 0; nt < NT; ++nt) {
            size_t bi = (((size_t)(ks * NT + nt)) * 64 + lane) * 8;
            short8 bh = *(const short8*)(Bh + bi);
            short8 bl = *(const short8*)(Bl + bi);
            acc[nt] = __builtin_amdgcn_mfma_f32_16x16x32_bf16(ah, bh, acc[nt], 0, 0, 0);
            acc[nt] = __builtin_amdgcn_mfma_f32_16x16x32_bf16(ah, bl, acc[nt], 0, 0, 0);
            acc[nt] = __builtin_amdgcn_mfma_f32_16x16x32_bf16(al, bh, acc[nt], 0, 0, 0);
        }
    }
    // D layout: row = quad*4 + reg, col = lane&15. All 16 rows of this wave share one pt.
    int pt = w >> 1, wi = w & 1;
    #pragma unroll
    for (int nt = 0; nt < NT; ++nt) {
        float m = fmaxf(fmaxf(acc[nt][0], acc[nt][1]), fmaxf(acc[nt][2], acc[nt][3]));
        m = fmaxf(m, __shfl_xor(m, 16, 64));
        m = fmaxf(m, __shfl_xor(m, 32, 64));
        if (lane < 16) red[pt][wi][nt * 16 + col] = m;
    }
    __syncthreads();
    for (int idx = t; idx < PTS * O; idx += 256) {
        int pp = idx / O, o = idx % O;
        float m = fmaxf(red[pp][0][o], red[pp][1][o]);
        size_t ni = (size_t)b * Np + n0 + pp;
        float v = lrelu(m + cb[ni * O + o]);
        Ypm[ni * O + o] = v;
        if (wcm) Ycm[((size_t)b * O + o) * Np + n0 + pp] = v;
    }
}

// Legacy fused EdgeConv for layer 1 (C=3): tiny W, all-in-one.
template<int C, int CPAD, int O, int OPT, int KPT, int PTS>
__global__ __launch_bounds__(256) void k_edgeconv(
    const float* __restrict__ Xpm, const int* __restrict__ idxg,
    const float* __restrict__ W, const float* __restrict__ sg, const float* __restrict__ bg,
    float* __restrict__ Ypm, float* __restrict__ Ycm, int wcm)
{
    constexpr int OG = O / OPT;
    constexpr int NKG = 256 / OG;
    constexpr int CL = CPAD + 4;
    static_assert(NKG * KPT == Kn, "k mapping");
    __shared__ float nbr[PTS][Kn][CL];
    __shared__ float ctr[PTS][CPAD];
    __shared__ float red[PTS][OPT][4][OG];
    int blk = blockIdx.x;
    int b = blk / (Np / PTS);
    int n0 = (blk % (Np / PTS)) * PTS;
    int t = threadIdx.x;
    int lane = t & 63, wid = t >> 6;
    const int* ip = idxg + ((size_t)b * Np + n0) * Kn;
    const float4* Xp4 = (const float4*)Xpm;
    constexpr int C4 = CPAD / 4;
    for (int e = t; e < PTS * C4; e += 256) {
        int pt = e / C4, c4 = e % C4;
        *(float4*)&ctr[pt][4 * c4] = Xp4[((size_t)b * Np + n0 + pt) * C4 + c4];
    }
    for (int e = t; e < PTS * Kn * C4; e += 256) {
        int pt = e / (Kn * C4);
        int r = e % (Kn * C4);
        int k = r / C4, c4 = r % C4;
        int nb = ip[pt * Kn + k];
        *(float4*)&nbr[pt][k][4 * c4] = Xp4[((size_t)b * Np + nb) * C4 + c4];
    }
    __syncthreads();
    int og = t % OG, kg = t / OG;
    float acc[PTS][OPT][KPT] = {};
    float ctt[PTS][OPT] = {};
    for (int c0 = 0; c0 < CPAD; c0 += 4) {
        float wn[OPT][4], wd[OPT][4];
        #pragma unroll
        for (int p = 0; p < OPT; ++p) {
            #pragma unroll
            for (int cc = 0; cc < 4; ++cc) {
                int c = c0 + cc;
                float a = (c < C) ? W[(size_t)(og + p * OG) * (2 * C) + c] : 0.f;
                float q = (c < C) ? W[(size_t)(og + p * OG) * (2 * C) + C + c] : 0.f;
                wn[p][cc] = a; wd[p][cc] = q - a;
            }
        }
        #pragma unroll
        for (int pt = 0; pt < PTS; ++pt) {
            float4 cv = *(const float4*)&ctr[pt][c0];
            #pragma unroll
            for (int p = 0; p < OPT; ++p) {
                ctt[pt][p] = fmaf(wd[p][0], cv.x, ctt[pt][p]);
                ctt[pt][p] = fmaf(wd[p][1], cv.y, ctt[pt][p]);
                ctt[pt][p] = fmaf(wd[p][2], cv.z, ctt[pt][p]);
                ctt[pt][p] = fmaf(wd[p][3], cv.w, ctt[pt][p]);
            }
        }
        #pragma unroll
        for (int pt = 0; pt < PTS; ++pt) {
            #pragma unroll
            for (int k = 0; k < KPT; ++k) {
                float4 nv = *(const float4*)&nbr[pt][kg * KPT + k][c0];
                #pragma unroll
                for (int p = 0; p < OPT; ++p) {
                    acc[pt][p][k] = fmaf(wn[p][0], nv.x, acc[pt][p][k]);
                    acc[pt][p][k] = fmaf(wn[p][1], nv.y, acc[pt][p][k]);
                    acc[pt][p][k] = fmaf(wn[p][2], nv.z, acc[pt][p][k]);
                    acc[pt][p][k] = fmaf(wn[p][3], nv.w, acc[pt][p][k]);
                }
            }
        }
    }
    #pragma unroll
    for (int pt = 0; pt < PTS; ++pt) {
        #pragma unroll
        for (int p = 0; p < OPT; ++p) {
            int o = og + p * OG;
            float sv = sg[o], bv = bg[o];
            float m = -INFINITY;
            #pragma unroll
            for (int k = 0; k < KPT; ++k) {
                float hv = fmaf(acc[pt][p][k] + ctt[pt][p], sv, bv);
                m = fmaxf(m, lrelu(hv));
            }
            #pragma unroll
            for (int s = OG; s < 64; s <<= 1) m = fmaxf(m, __shfl_xor(m, s, 64));
            if (lane < OG) red[pt][p][wid][lane] = m;
        }
    }
    __syncthreads();
    if (t < OG) {
        #pragma unroll
        for (int pt = 0; pt < PTS; ++pt) {
            #pragma unroll
            for (int p = 0; p < OPT; ++p) {
                float m = fmaxf(fmaxf(red[pt][p][0][t], red[pt][p][1][t]),
                                fmaxf(red[pt][p][2][t], red[pt][p][3][t]));
                int o = t + p * OG;
                Ypm[((size_t)b * Np + n0 + pt) * O + o] = m;
                if (wcm) Ycm[((size_t)b * O + o) * Np + n0 + pt] = m;
            }
        }
    }
}

// W5 transpose [1024][512] -> [512][1024] (32x32 LDS tiles)
__global__ __launch_bounds__(256) void k_w5t(const float* __restrict__ W5, float* __restrict__ W5t) {
    __shared__ float tile[32][33];
    int o0 = (blockIdx.x & 31) * 32;
    int c0 = (blockIdx.x >> 5) * 32;
    int lr = threadIdx.x >> 5, lc = threadIdx.x & 31;
    #pragma unroll
    for (int j = 0; j < 4; ++j) {
        int r = lr + 8 * j;
        tile[r][lc] = W5[(size_t)(o0 + r) * 512 + c0 + lc];
    }
    __syncthreads();
    #pragma unroll
    for (int j = 0; j < 4; ++j) {
        int r = lr + 8 * j;
        W5t[(size_t)(c0 + r) * 1024 + o0 + lc] = tile[lc][r];
    }
}

// W5 (channel-major W5t) + BN + LeakyReLU + per-block max/sum over 32 points -> partials.
__global__ __launch_bounds__(256) void k_w5pool(
    const float* __restrict__ x1, const float* __restrict__ x2,
    const float* __restrict__ x3, const float* __restrict__ x4,
    const float* __restrict__ W5t, const float* __restrict__ s5, const float* __restrict__ b5,
    float* __restrict__ pmax, float* __restrict__ psum)
{
    constexpr int PP = 16;
    __shared__ float cat[PP][512];
    int blk = blockIdx.x;
    int b = blk >> 6;
    int chunk = blk & 63;
    int n0 = chunk * 32;
    int t = threadIdx.x;
    float mx[4] = {-INFINITY, -INFINITY, -INFINITY, -INFINITY};
    float sm[4] = {};
    for (int pass = 0; pass < 2; ++pass) {
        __syncthreads();
        for (int e = t; e < PP * 128; e += 256) {
            int pt = e >> 7, c4 = e & 127;
            size_t pi = (size_t)b * Np + n0 + pass * PP + pt;
            float4 v;
            if (c4 < 16)      v = ((const float4*)x1)[pi * 16 + c4];
            else if (c4 < 32) v = ((const float4*)x2)[pi * 16 + (c4 - 16)];
            else if (c4 < 64) v = ((const float4*)x3)[pi * 32 + (c4 - 32)];
            else              v = ((const float4*)x4)[pi * 64 + (c4 - 64)];
            *(float4*)&cat[pt][4 * c4] = v;
        }
        __syncthreads();
        float acc[4][PP] = {};
        for (int c0 = 0; c0 < 512; c0 += 4) {
            float wv[4][4];
            #pragma unroll
            for (int j = 0; j < 4; ++j) {
                const float* row = W5t + (size_t)(c0 + j) * 1024 + t;
                #pragma unroll
                for (int r = 0; r < 4; ++r) wv[j][r] = row[256 * r];
            }
            #pragma unroll
            for (int pt = 0; pt < PP; ++pt) {
                float4 cv = *(const float4*)&cat[pt][c0];
                #pragma unroll
                for (int r = 0; r < 4; ++r) {
                    acc[r][pt] = fmaf(wv[0][r], cv.x, acc[r][pt]);
                    acc[r][pt] = fmaf(wv[1][r], cv.y, acc[r][pt]);
                    acc[r][pt] = fmaf(wv[2][r], cv.z, acc[r][pt]);
                    acc[r][pt] = fmaf(wv[3][r], cv.w, acc[r][pt]);
                }
            }
        }
        #pragma unroll
        for (int r = 0; r < 4; ++r) {
            int o = t + 256 * r;
            float sv = s5[o], bv = b5[o];
            #pragma unroll
            for (int pt = 0; pt < PP; ++pt) {
                float v = lrelu(fmaf(acc[r][pt], sv, bv));
                mx[r] = fmaxf(mx[r], v);
                sm[r] += v;
            }
        }
    }
    #pragma unroll
    for (int r = 0; r < 4; ++r) {
        int o = t + 256 * r;
        pmax[((size_t)(b * 64 + chunk)) * 1024 + o] = mx[r];
        psum[((size_t)(b * 64 + chunk)) * 1024 + o] = sm[r];
    }
}

__global__ __launch_bounds__(256) void k_poolred(const float* __restrict__ pmax, const float* __restrict__ psum,
                                                 float* __restrict__ g0) {
    int i = blockIdx.x * 256 + threadIdx.x;
    int b = i >> 10, o = i & 1023;
    float mx = -INFINITY, sm = 0.f;
    for (int ch = 0; ch < 64; ++ch) {
        size_t idx = ((size_t)(b * 64 + ch)) * 1024 + o;
        mx = fmaxf(mx, pmax[idx]);
        sm += psum[idx];
    }
    g0[(size_t)b * 2048 + o] = mx;
    g0[(size_t)b * 2048 + 1024 + o] = sm * (1.f / Np);
}

__global__ __launch_bounds__(256) void k_fc(const float* __restrict__ In, int ldIn, int C,
                                            const float* __restrict__ Wm,
                                            const float* __restrict__ bias,
                                            const float* __restrict__ sc, const float* __restrict__ bnb,
                                            int leaky, float* __restrict__ Out, int ldOut, int O) {
    int wid = threadIdx.x >> 6, lane = threadIdx.x & 63;
    int o = blockIdx.x * 4 + wid;
    int b = blockIdx.y;
    if (o >= O) return;
    const float* in = In + (size_t)b * ldIn;
    const float* wr = Wm + (size_t)o * C;
    float acc = 0.f;
    for (int c = lane; c < C; c += 64) acc = fmaf(in[c], wr[c], acc);
    #pragma unroll
    for (int off = 32; off; off >>= 1) acc += __shfl_down(acc, off, 64);
    if (lane == 0) {
        float v = acc + (bias ? bias[o] : 0.f);
        if (sc) v = fmaf(v, sc[o], bnb[o]);
        if (leaky) v = lrelu(v);
        Out[(size_t)b * ldOut + o] = v;
    }
}

extern "C" void kernel_launch(void* const* d_in, const int* in_sizes, int n_in,
                              void* d_out, int out_size, void* d_ws, size_t ws_size,
                              hipStream_t stream) {
    const float* x   = (const float*)d_in[0];
    const float* W1  = (const float*)d_in[1];
    const float* s1  = (const float*)d_in[2];
    const float* b1  = (const float*)d_in[3];
    const float* W2  = (const float*)d_in[4];
    const float* s2  = (const float*)d_in[5];
    const float* b2  = (const float*)d_in[6];
    const float* W3  = (const float*)d_in[7];
    const float* s3  = (const float*)d_in[8];
    const float* b3  = (const float*)d_in[9];
    const float* W4  = (const float*)d_in[10];
    const float* s4  = (const float*)d_in[11];
    const float* b4  = (const float*)d_in[12];
    const float* W5  = (const float*)d_in[13];
    const float* s5  = (const float*)d_in[14];
    const float* b5  = (const float*)d_in[15];
    const float* L1w = (const float*)d_in[16];
    const float* s6  = (const float*)d_in[17];
    const float* b6  = (const float*)d_in[18];
    const float* L2w = (const float*)d_in[19];
    const float* L2b = (const float*)d_in[20];
    const float* s7  = (const float*)d_in[21];
    const float* b7  = (const float*)d_in[22];
    const float* L3w = (const float*)d_in[23];
    const float* L3b = (const float*)d_in[24];
    const float* F1w = (const float*)d_in[25];
    const float* s8  = (const float*)d_in[26];
    const float* b8  = (const float*)d_in[27];
    const float* F2w = (const float*)d_in[28];
    const float* F2b = (const float*)d_in[29];
    const float* s9  = (const float*)d_in[30];
    const float* b9  = (const float*)d_in[31];
    const float* F3w = (const float*)d_in[32];
    const float* F3b = (const float*)d_in[33];

    float* ws = (float*)d_ws;
    size_t off = 0;
    auto alloc = [&](size_t n) { float* p = ws + off; off += n; return p; };
    float* pts  = alloc((size_t)Bn * Np * 4);
    float* x1   = alloc((size_t)Bn * Np * 64);
    float* x2   = alloc((size_t)Bn * Np * 64);
    float* x3   = alloc((size_t)Bn * Np * 128);
    float* x4   = alloc((size_t)Bn * Np * 256);
    float* xcm  = alloc((size_t)Bn * Np * 128);
    float* xxb  = alloc((size_t)Bn * Np);
    int*   idxb = (int*)alloc((size_t)Bn * Np * Kn);
    float* g0   = alloc((size_t)Bn * 2048);
    float* g1   = alloc((size_t)Bn * 512);
    float* g2   = alloc((size_t)Bn * 256);
    float* y1   = alloc((size_t)Bn * 512);
    float* y2   = alloc((size_t)Bn * 256);
    float* WnsT2 = alloc(64 * 64);
    float* WdsT2 = alloc(64 * 64);
    float* WnsT3 = alloc(64 * 128);
    float* WdsT3 = alloc(64 * 128);
    float* WnsT4 = alloc(128 * 256);
    float* WdsT4 = alloc(128 * 256);
    ushortT* Bh2 = (ushortT*)alloc(64 * 64 / 2);
    ushortT* Bl2 = (ushortT*)alloc(64 * 64 / 2);
    ushortT* Bh3 = (ushortT*)alloc(64 * 128 / 2);
    ushortT* Bl3 = (ushortT*)alloc(64 * 128 / 2);
    ushortT* Bh4 = (ushortT*)alloc(128 * 256 / 2);
    ushortT* Bl4 = (ushortT*)alloc(128 * 256 / 2);
    // alias into xcm (dead after last knn): W5t (512K) + pmax (512K) + psum (512K)
    float* W5t  = xcm;
    float* pmax = xcm + 524288;
    float* psum = xcm + 1048576;
    // cb buffers alias the layer outputs (read-then-write per element)
    float* cb2 = x2;
    float* cb3 = x3;
    float* cb4 = x4;

    k_transpose<<<Bn * Np / 256, 256, 0, stream>>>(x, pts);
    k_wsplit<<<16, 256, 0, stream>>>(W2, s2, 64, 64, WnsT2, WdsT2);
    k_wsplit<<<32, 256, 0, stream>>>(W3, s3, 64, 128, WnsT3, WdsT3);
    k_wsplit<<<128, 256, 0, stream>>>(W4, s4, 128, 256, WnsT4, WdsT4);
    k_wpack<<<16, 256, 0, stream>>>(W2, s2, 64, 64, Bh2, Bl2);
    k_wpack<<<32, 256, 0, stream>>>(W3, s3, 64, 128, Bh3, Bl3);
    k_wpack<<<128, 256, 0, stream>>>(W4, s4, 128, 256, Bh4, Bl4);

    // Layer 1: C=3 (cm = input x directly)
    k_xx<<<Bn * Np / 4, 256, 0, stream>>>(pts, xxb, 3, 4);
    k_knn<3><<<Bn * Np / 4, 256, 0, stream>>>(x, pts, 4, xxb, idxb);
    k_edgeconv<3, 4, 64, 1, 8, 4><<<Bn * Np / 4, 256, 0, stream>>>(pts, idxb, W1, s1, b1, x1, xcm, 1);

    // Layer 2: C=64 -> O=64
    k_xx<<<Bn * Np / 4, 256, 0, stream>>>(x1, xxb, 64, 64);
    k_knn<64><<<Bn * Np / 4, 256, 0, stream>>>(xcm, x1, 64, xxb, idxb);
    k_ctr<64, 64, 4><<<Bn * Np / 32, 256, 0, stream>>>(x1, WdsT2, b2, cb2);
    k_ec3<64, 64, 2><<<Bn * Np / 2, 256, 0, stream>>>(x1, idxb, Bh2, Bl2, cb2, x2, xcm, 1);

    // Layer 3: C=64 -> O=128
    k_xx<<<Bn * Np / 4, 256, 0, stream>>>(x2, xxb, 64, 64);
    k_knn<64><<<Bn * Np / 4, 256, 0, stream>>>(xcm, x2, 64, xxb, idxb);
    k_ctr<64, 128, 8><<<Bn * Np / 32, 256, 0, stream>>>(x2, WdsT3, b3, cb3);
    k_ec3<64, 128, 2><<<Bn * Np / 2, 256, 0, stream>>>(x2, idxb, Bh3, Bl3, cb3, x3, xcm, 1);

    // Layer 4: C=128 -> O=256
    k_xx<<<Bn * Np / 4, 256, 0, stream>>>(x3, xxb, 128, 128);
    k_knn<128><<<Bn * Np / 4, 256, 0, stream>>>(xcm, x3, 128, xxb, idxb);
    // xcm dead from here; W5t/pmax/psum alias it
    k_w5t<<<512, 256, 0, stream>>>(W5, W5t);
    k_ctr<128, 256, 8><<<Bn * Np / 32, 256, 0, stream>>>(x3, WdsT4, b4, cb4);
    k_ec3<128, 256, 2><<<Bn * Np / 2, 256, 0, stream>>>(x3, idxb, Bh4, Bl4, cb4, x4, nullptr, 0);

    // W5 + pooling (atomic-free)
    k_w5pool<<<Bn * 64, 256, 0, stream>>>(x1, x2, x3, x4, W5t, s5, b5, pmax, psum);
    k_poolred<<<Bn * 1024 / 256, 256, 0, stream>>>(pmax, psum, g0);

    float* out = (float*)d_out;
    k_fc<<<dim3(128, Bn), 256, 0, stream>>>(g0, 2048, 2048, L1w, nullptr, s6, b6, 1, g1, 512, 512);
    k_fc<<<dim3(64, Bn), 256, 0, stream>>>(g1, 512, 512, L2w, L2b, s7, b7, 1, g2, 256, 256);
    k_fc<<<dim3(2, Bn), 256, 0, stream>>>(g2, 256, 256, L3w, L3b, nullptr, nullptr, 0, out, 5, 5);
    k_fc<<<dim3(128, Bn), 256, 0, stream>>>(g0, 2048, 1024, F1w, nullptr, s8, b8, 1, y1, 512, 512);
    k_fc<<<dim3(64, Bn), 256, 0, stream>>>(y1, 512, 512, F2w, F2b, s9, b9, 1, y2, 256, 256);
    k_fc<<<dim3(2, Bn), 256, 0, stream>>>(y2, 256, 256, F3w, F3b, nullptr, nullptr, 0, out + 40, 5, 5);
}